// Round 10
// baseline (229.803 us; speedup 1.0000x reference)
//
#include <hip/hip_runtime.h>
#include <stdint.h>

#define B_  32
#define D_  192
#define TX_ 256
#define TY_ 1024
#define NEGV -1e9f
// -0.5*log(2*pi)*D, computed in double, cast to f32 (matches reference const)
#define LPCONST ((float)(-176.43619837529715))

// ---------------- K0: row/col squared-norm terms -------------------------
__global__ __launch_bounds__(256) void k0_sq(const float* __restrict__ x,
                                             const float* __restrict__ y,
                                             float* __restrict__ xsq,
                                             float* __restrict__ ysq) {
    int gid = blockIdx.x * 256 + threadIdx.x;
    if (gid < B_ * TX_) {
        int b = gid >> 8, t = gid & 255;
        const float* p = x + (size_t)b * D_ * TX_ + t;
        float s = 0.f;
        #pragma unroll 8
        for (int d = 0; d < D_; ++d) { float v = p[(size_t)d * TX_]; s += v * v; }
        xsq[gid] = -0.5f * s;
    } else {
        int g = gid - B_ * TX_;
        int b = g >> 10, t = g & 1023;
        const float* p = y + (size_t)b * D_ * TY_ + t;
        float s = 0.f;
        #pragma unroll 8
        for (int d = 0; d < D_; ++d) { float v = p[(size_t)d * TY_]; s += v * v; }
        ysq[g] = -0.5f * s;
    }
}

// ---------------- K1: log_prior GEMM ------------------------------------
#define BT 128
#define BS 128
#define BK 32
__global__ __launch_bounds__(256) void k1_gemm(const float* __restrict__ x,
                                               const float* __restrict__ y,
                                               const float* __restrict__ xsq,
                                               const float* __restrict__ ysq,
                                               float* __restrict__ lp) {
    __shared__ float xs[BK][BT];
    __shared__ float ys[BK][BS];
    const int id = blockIdx.x;            // 0..511
    const int r  = id & 7;
    const int g  = id >> 3;               // 0..63
    const int b  = r + 8 * (g >> 4);      // 0..31
    const int sub = g & 15;               // 16 tiles per batch
    const int t0 = (sub >> 3) * BT;       // 2 t-tiles
    const int s0 = (sub & 7) * BS;        // 8 s-tiles
    const int tid = threadIdx.x;
    const int ti = tid & 15;   // t-group (fast dim -> coalesced stores)
    const int si = tid >> 4;   // s-group

    float acc[8][8];
    #pragma unroll
    for (int i = 0; i < 8; ++i)
        #pragma unroll
        for (int j = 0; j < 8; ++j) acc[i][j] = 0.f;

    const float* xg = x + (size_t)b * D_ * TX_ + t0;
    const float* yg = y + (size_t)b * D_ * TY_ + s0;

    for (int k0 = 0; k0 < D_; k0 += BK) {
        #pragma unroll
        for (int i = 0; i < 4; ++i) {
            int f = tid + i * 256;           // 0..1023 float4 slots
            int row = f >> 5;                // 0..31
            int col = (f & 31) * 4;          // 0..124
            float4 v = *(const float4*)(xg + (size_t)(k0 + row) * TX_ + col);
            *(float4*)&xs[row][col] = v;
            float4 w = *(const float4*)(yg + (size_t)(k0 + row) * TY_ + col);
            *(float4*)&ys[row][col] = w;
        }
        __syncthreads();
        #pragma unroll
        for (int k = 0; k < BK; ++k) {
            float xr[8], yr[8];
            *(float4*)&xr[0] = *(float4*)&xs[k][ti * 8];
            *(float4*)&xr[4] = *(float4*)&xs[k][ti * 8 + 4];
            *(float4*)&yr[0] = *(float4*)&ys[k][si * 8];
            *(float4*)&yr[4] = *(float4*)&ys[k][si * 8 + 4];
            #pragma unroll
            for (int i = 0; i < 8; ++i)
                #pragma unroll
                for (int j = 0; j < 8; ++j) acc[i][j] += xr[i] * yr[j];
        }
        __syncthreads();
    }

    float xq[8], yq[8];
    *(float4*)&xq[0] = *(const float4*)(xsq + b * TX_ + t0 + ti * 8);
    *(float4*)&xq[4] = *(const float4*)(xsq + b * TX_ + t0 + ti * 8 + 4);
    *(float4*)&yq[0] = *(const float4*)(ysq + b * TY_ + s0 + si * 8);
    *(float4*)&yq[4] = *(const float4*)(ysq + b * TY_ + s0 + si * 8 + 4);

    #pragma unroll
    for (int js = 0; js < 8; ++js) {
        float* op = lp + (size_t)(b * TY_ + s0 + si * 8 + js) * TX_ + t0 + ti * 8;
        float o[8];
        #pragma unroll
        for (int it = 0; it < 8; ++it) {
            float v = yq[js] + acc[it][js];
            v = v + xq[it];
            o[it] = v + LPCONST;
        }
        *(float4*)op       = *(float4*)&o[0];
        *(float4*)(op + 4) = *(float4*)&o[4];
    }
}

// ---------------- K1.5: cache-warm lp for the DP -------------------------
__global__ __launch_bounds__(256) void k15_warm(const float* __restrict__ lp,
                                                const int* __restrict__ xlens) {
    const int p  = blockIdx.x;             // 0..255
    const int r  = p & 7;
    const int b  = r + 8 * ((p >> 3) & 3);
    const int c0 = (p >> 5) * 128;
    const int xlen = xlens[b];
    const int tid = threadIdx.x;
    const int e = (tid & 63) * 4;
    const float* base = lp + (size_t)b * TY_ * TX_;
    float acc = 0.f;
    if (e < xlen) {
        #pragma unroll 8
        for (int it = 0; it < 32; ++it) {
            int col = c0 + it * 4 + (tid >> 6);
            float4 v = *(const float4*)(base + (size_t)col * TX_ + e);
            acc += v.x + v.y + v.z + v.w;  // keep loads live
        }
    }
    asm volatile("" :: "v"(acc));
}

// ---- DPP whole-wave lane ops -------------------------------------------
// wave_shr:1 (0x138): lane N <- lane N-1, lane 0 <- old (0, masked later)
__device__ __forceinline__ float wshr1(float v) {
    int r = __builtin_amdgcn_update_dpp(0, __float_as_int(v),
                                        0x138, 0xF, 0xF, false);
    return __int_as_float(r);
}
// wave_ror:1 (0x13C): lane N <- lane N-1, lane 0 <- lane 63
__device__ __forceinline__ float wror1(float v) {
    int r = __builtin_amdgcn_update_dpp(0, __float_as_int(v),
                                        0x13C, 0xF, 0xF, false);
    return __int_as_float(r);
}

// ---------------- K2: forward DP + backtrack (strided rows) -------------
// One wave per batch. Lane l owns rows {l, l+64, l+128, l+192} — so every
// prev[t-1] is cross-lane (DPP) and the 4 per-lane updates are PARALLEL,
// killing the intra-column c0->c1->c2->c3 serial chain of the contiguous
// layout (R6 ablation: that chain was the dominant ~180cy/col term).
// Lane 0's row 64k needs prev[64k-1] = lane 63's element k-1: wave_ror:1
// of element k-1 selects it. Loads: 4 coalesced 256B dword loads/column,
// xlen-clamping folded into the 4 base pointers (branch-free, once).
__global__ __launch_bounds__(64, 1) void k2_dp(const float* __restrict__ lp,
                                               const int* __restrict__ xlens,
                                               const int* __restrict__ ylens,
                                               unsigned char* __restrict__ path) {
    __shared__ unsigned int RB[TX_][33];   // padded stride (33: bank = l+w)
    __shared__ unsigned int PTw[TY_ / 4];  // path bytes staged as words
    unsigned char* PT = (unsigned char*)PTw;

    const int b = blockIdx.x;
    const int l = threadIdx.x;
    const int xlen = xlens[b];
    const int ylen = ylens[b];
    const int send = (ylen + 31) & ~31;    // >=512, multiple of 32
    const float* lpb = lp + (size_t)b * TY_ * TX_;
    // rows for elements 0..3; invalid rows clamp to last valid row's line
    const float* base0 = lpb + l;                                    // l<64<=xlen
    const float* base1 = lpb + ((l + 64  < xlen) ? (l + 64)  : (xlen - 1));
    const float* base2 = lpb + ((l + 128 < xlen) ? (l + 128) : (xlen - 1));
    const float* base3 = lpb + ((l + 192 < xlen) ? (l + 192) : (xlen - 1));

#define LD4(j, s) { int sc = ((s) < TY_) ? (s) : (TY_ - 1);             \
    g0[j] = base0[(size_t)sc * TX_]; g1[j] = base1[(size_t)sc * TX_];   \
    g2[j] = base2[(size_t)sc * TX_]; g3[j] = base3[(size_t)sc * TX_]; }

// column s: shifts/bits from column (s-1) values, then parallel update.
#define PROCS(s, j, PRE) {                                              \
    unsigned int sbit = 1u << ((s) & 31);                               \
    float a0 = wshr1(v0), a1 = wshr1(v1), a2 = wshr1(v2), a3 = wshr1(v3); \
    float q0 = wror1(v0), q1 = wror1(v1), q2 = wror1(v2);               \
    float s1v = (l == 0) ? q0 : a1;                                     \
    float s2v = (l == 0) ? q1 : a2;                                     \
    float s3v = (l == 0) ? q2 : a3;                                     \
    bool e0 = false, e1 = false, e2 = false, e3 = false;                \
    if (PRE) { e0 = (l == (s));        e1 = (l + 64 == (s));            \
               e2 = (l + 128 == (s));  e3 = (l + 192 == (s)); }         \
    if ((l != 0) && (e0 || (a0  > v0))) rw0 |= sbit;                    \
    if (e1 || (s1v > v1)) rw1 |= sbit;                                  \
    if (e2 || (s2v > v2)) rw2 |= sbit;                                  \
    if (e3 || (s3v > v3)) rw3 |= sbit;                                  \
    v0 = g0[j] + fmaxf(e0 ? NEGV : v0, (l == 0) ? NEGV : a0);           \
    v1 = g1[j] + fmaxf(e1 ? NEGV : v1, s1v);                            \
    v2 = g2[j] + fmaxf(e2 ? NEGV : v2, s2v);                            \
    v3 = g3[j] + fmaxf(e3 ? NEGV : v3, s3v);                            \
}

#define FLUSH(w) { RB[l][w] = rw0; RB[l + 64][w] = rw1;                 \
                   RB[l + 128][w] = rw2; RB[l + 192][w] = rw3;          \
                   rw0 = rw1 = rw2 = rw3 = 0; }

    float g0[16], g1[16], g2[16], g3[16];
    #pragma unroll
    for (int i = 0; i < 16; ++i) LD4(i, i)

    float v0, v1, v2, v3;
    unsigned int rw0 = 0, rw1 = 0, rw2 = 0, rw3 = 0;

    // s = 0: col0 = where(t==0, lp, NEG); only lane0/elem0 is row 0
    v0 = (l == 0) ? g0[0] : NEGV;
    v1 = NEGV; v2 = NEGV; v3 = NEGV;
    LD4(0, 16)

    #pragma unroll
    for (int j = 1; j < 16; ++j) { PROCS(j, j, true) LD4(j, 16 + j) }

    #pragma unroll 1
    for (int sb = 16; sb < 256; sb += 16) {
        #pragma unroll
        for (int j = 0; j < 16; ++j) { PROCS(sb + j, j, true) LD4(j, sb + 16 + j) }
        if (((sb + 15) & 31) == 31) FLUSH((sb + 15) >> 5)
    }
    #pragma unroll 1
    for (int sb = 256; sb < send; sb += 16) {
        #pragma unroll
        for (int j = 0; j < 16; ++j) { PROCS(sb + j, j, false) LD4(j, sb + 16 + j) }
        if (((sb + 15) & 31) == 31) FLUSH((sb + 15) >> 5)
    }
    __syncthreads();

    if (l == 0) {
        // run-length backtrack with speculative 'below' word prefetch.
        int idx = xlen - 1;
        int yi = ylen - 1;
        int w = yi >> 5;
        unsigned int cur = RB[idx][w];
        unsigned int below = (idx > 0) ? RB[idx - 1][w] : 0u;
        while (yi >= 0) {
            unsigned int m = cur & (0xFFFFFFFFu >> (31 - (yi & 31)));
            if (m) {
                int hb = 31 - __clz(m);
                int lo = (w << 5) + hb;           // move happens at col lo
                for (int q = lo; q <= yi; ++q) PT[q] = (unsigned char)idx;
                --idx;
                cur = below;
                below = (idx > 0) ? RB[idx - 1][w] : 0u;
                yi = lo - 1;
                if (yi >= 0 && (yi >> 5) < w) {
                    w = yi >> 5;
                    cur = RB[idx][w];
                    below = (idx > 0) ? RB[idx - 1][w] : 0u;
                }
            } else {
                int lo = w << 5;
                for (int q = lo; q <= yi; ++q) PT[q] = (unsigned char)idx;
                yi = lo - 1;
                if (yi >= 0) {
                    --w;
                    cur = RB[idx][w];
                    below = (idx > 0) ? RB[idx - 1][w] : 0u;
                }
            }
        }
    }
    __syncthreads();
    {
        unsigned int* pd = (unsigned int*)(path + b * TY_);
        #pragma unroll
        for (int k = 0; k < 4; ++k) pd[l + k * 64] = PTw[l + k * 64];
    }
}

// ---------------- K3: materialize one-hot output ------------------------
__global__ __launch_bounds__(256) void k3_out(const unsigned char* __restrict__ path,
                                              const int* __restrict__ ylens,
                                              float* __restrict__ out) {
    int F = blockIdx.x * 256 + threadIdx.x;       // float4 index, 2M total
    int yi = (F & 255) * 4;
    int t  = (F >> 8) & 255;
    int b  = F >> 16;
    int ylen = ylens[b];
    unsigned int pw = *(const unsigned int*)(path + b * TY_ + yi);
    float4 v;
    v.x = (((pw      ) & 255u) == (unsigned)t && yi     < ylen) ? 1.f : 0.f;
    v.y = (((pw >>  8) & 255u) == (unsigned)t && yi + 1 < ylen) ? 1.f : 0.f;
    v.z = (((pw >> 16) & 255u) == (unsigned)t && yi + 2 < ylen) ? 1.f : 0.f;
    v.w = (((pw >> 24) & 255u) == (unsigned)t && yi + 3 < ylen) ? 1.f : 0.f;
    ((float4*)out)[F] = v;
}

extern "C" void kernel_launch(void* const* d_in, const int* in_sizes, int n_in,
                              void* d_out, int out_size, void* d_ws, size_t ws_size,
                              hipStream_t stream) {
    const float* x  = (const float*)d_in[0];
    const int*   xl = (const int*)d_in[1];
    const float* y  = (const float*)d_in[2];
    const int*   yl = (const int*)d_in[3];
    float* out = (float*)d_out;

    char* ws = (char*)d_ws;
    float* xsq = (float*)ws;                           //  32 KB
    float* ysq = (float*)(ws + 32 * 1024);             // 128 KB
    unsigned char* path = (unsigned char*)(ws + 160 * 1024); // 32 KB

    // reuse d_out (exactly B*TY*TX floats = 32 MB) as log_prior scratch;
    // K3 fully overwrites it afterwards.
    float* lp = out;

    k0_sq   <<<160, 256, 0, stream>>>(x, y, xsq, ysq);
    k1_gemm <<<512, 256, 0, stream>>>(x, y, xsq, ysq, lp);
    k15_warm<<<256, 256, 0, stream>>>(lp, xl);
    k2_dp   <<<B_, 64, 0, stream>>>(lp, xl, yl, path);
    k3_out  <<<(B_ * TX_ * TY_ / 4) / 256, 256, 0, stream>>>(path, yl, out);
}

// Round 12
// 198.004 us; speedup vs baseline: 1.1606x; 1.1606x over previous
//
#include <hip/hip_runtime.h>
#include <stdint.h>

#define B_  32
#define D_  192
#define TX_ 256
#define TY_ 1024
#define NEGV -1e9f
// -0.5*log(2*pi)*D, computed in double, cast to f32 (matches reference const)
#define LPCONST ((float)(-176.43619837529715))

// ---------------- K0: row/col squared-norm terms -------------------------
__global__ __launch_bounds__(256) void k0_sq(const float* __restrict__ x,
                                             const float* __restrict__ y,
                                             float* __restrict__ xsq,
                                             float* __restrict__ ysq) {
    int gid = blockIdx.x * 256 + threadIdx.x;
    if (gid < B_ * TX_) {
        int b = gid >> 8, t = gid & 255;
        const float* p = x + (size_t)b * D_ * TX_ + t;
        float s = 0.f;
        #pragma unroll 8
        for (int d = 0; d < D_; ++d) { float v = p[(size_t)d * TX_]; s += v * v; }
        xsq[gid] = -0.5f * s;
    } else {
        int g = gid - B_ * TX_;
        int b = g >> 10, t = g & 1023;
        const float* p = y + (size_t)b * D_ * TY_ + t;
        float s = 0.f;
        #pragma unroll 8
        for (int d = 0; d < D_; ++d) { float v = p[(size_t)d * TY_]; s += v * v; }
        ysq[g] = -0.5f * s;
    }
}

// ---------------- K1: log_prior GEMM ------------------------------------
#define BT 128
#define BS 128
#define BK 32
__global__ __launch_bounds__(256) void k1_gemm(const float* __restrict__ x,
                                               const float* __restrict__ y,
                                               const float* __restrict__ xsq,
                                               const float* __restrict__ ysq,
                                               float* __restrict__ lp) {
    __shared__ float xs[BK][BT];
    __shared__ float ys[BK][BS];
    const int id = blockIdx.x;            // 0..511
    const int r  = id & 7;
    const int g  = id >> 3;               // 0..63
    const int b  = r + 8 * (g >> 4);      // 0..31
    const int sub = g & 15;               // 16 tiles per batch
    const int t0 = (sub >> 3) * BT;       // 2 t-tiles
    const int s0 = (sub & 7) * BS;        // 8 s-tiles
    const int tid = threadIdx.x;
    const int ti = tid & 15;   // t-group (fast dim -> coalesced stores)
    const int si = tid >> 4;   // s-group

    float acc[8][8];
    #pragma unroll
    for (int i = 0; i < 8; ++i)
        #pragma unroll
        for (int j = 0; j < 8; ++j) acc[i][j] = 0.f;

    const float* xg = x + (size_t)b * D_ * TX_ + t0;
    const float* yg = y + (size_t)b * D_ * TY_ + s0;

    for (int k0 = 0; k0 < D_; k0 += BK) {
        #pragma unroll
        for (int i = 0; i < 4; ++i) {
            int f = tid + i * 256;           // 0..1023 float4 slots
            int row = f >> 5;                // 0..31
            int col = (f & 31) * 4;          // 0..124
            float4 v = *(const float4*)(xg + (size_t)(k0 + row) * TX_ + col);
            *(float4*)&xs[row][col] = v;
            float4 w = *(const float4*)(yg + (size_t)(k0 + row) * TY_ + col);
            *(float4*)&ys[row][col] = w;
        }
        __syncthreads();
        #pragma unroll
        for (int k = 0; k < BK; ++k) {
            float xr[8], yr[8];
            *(float4*)&xr[0] = *(float4*)&xs[k][ti * 8];
            *(float4*)&xr[4] = *(float4*)&xs[k][ti * 8 + 4];
            *(float4*)&yr[0] = *(float4*)&ys[k][si * 8];
            *(float4*)&yr[4] = *(float4*)&ys[k][si * 8 + 4];
            #pragma unroll
            for (int i = 0; i < 8; ++i)
                #pragma unroll
                for (int j = 0; j < 8; ++j) acc[i][j] += xr[i] * yr[j];
        }
        __syncthreads();
    }

    float xq[8], yq[8];
    *(float4*)&xq[0] = *(const float4*)(xsq + b * TX_ + t0 + ti * 8);
    *(float4*)&xq[4] = *(const float4*)(xsq + b * TX_ + t0 + ti * 8 + 4);
    *(float4*)&yq[0] = *(const float4*)(ysq + b * TY_ + s0 + si * 8);
    *(float4*)&yq[4] = *(const float4*)(ysq + b * TY_ + s0 + si * 8 + 4);

    #pragma unroll
    for (int js = 0; js < 8; ++js) {
        float* op = lp + (size_t)(b * TY_ + s0 + si * 8 + js) * TX_ + t0 + ti * 8;
        float o[8];
        #pragma unroll
        for (int it = 0; it < 8; ++it) {
            float v = yq[js] + acc[it][js];
            v = v + xq[it];
            o[it] = v + LPCONST;
        }
        *(float4*)op       = *(float4*)&o[0];
        *(float4*)(op + 4) = *(float4*)&o[4];
    }
}

// ---- DPP whole-wave shift: lane N <- lane N-1 (wave_shr:1 = 0x138) -----
__device__ __forceinline__ float wshr1(float v) {
    int r = __builtin_amdgcn_update_dpp(0, __float_as_int(v),
                                        0x138, 0xF, 0xF, false);
    return __int_as_float(r);
}

// ---------------- K2: forward DP + backtrack (4-wave pipeline) ----------
// Block = 256 threads = 4 waves per batch. Wave w owns rows 64w+l (1 row
// per lane). Waves march through 32-column groups in a barrier-lockstep
// staircase: in phase p, wave w processes group p-w. Row-(64w-1) boundary
// values flow from wave w-1 through a 128-slot LDS ring (lane 63 writes,
// reader reads one phase later; ring regions k%4 vs (k-1..k-2)%4 disjoint).
// Per-column per-wave: 1 DPP + ~13 VALU + 1 coalesced dword load — no
// intra-column serial chain (R6's 180cy/col term quartered + parallelized).
// Exact f32 op order per cell preserved -> bit-identical path.
__global__ __launch_bounds__(256, 1) void k2_dp(const float* __restrict__ lp,
                                                const int* __restrict__ xlens,
                                                const int* __restrict__ ylens,
                                                unsigned char* __restrict__ path) {
    __shared__ unsigned int RB[TX_][33];   // backpointer bits, padded stride
    __shared__ unsigned int PTw[TY_ / 4];  // path bytes staged as words
    __shared__ float bnd[4][128];          // boundary ring (wave w row 64w+63)
    unsigned char* PT = (unsigned char*)PTw;

    const int tid = threadIdx.x;
    const int w   = tid >> 6;              // wave 0..3
    const int l   = tid & 63;
    const int b   = blockIdx.x;
    const int xlen = xlens[b];
    const int ylen = ylens[b];
    const int send = (ylen + 31) & ~31;    // >=512, multiple of 32
    const int groups = send >> 5;          // 16..32
    const int row  = (w << 6) + l;
    const int rowc = (row < xlen) ? row : (xlen - 1);   // clamp (traffic)
    const float* base = lp + (size_t)b * TY_ * TX_ + rowc;
    const bool isL0  = (l == 0);
    const bool tzero = (row == 0);
    const bool pub   = (w < 3) && (l == 63);

    float r[32];                           // 32-column load ring (static idx)
    #pragma unroll
    for (int j = 0; j < 32; ++j) r[j] = base[(size_t)j * TX_];

    float v = NEGV;
    unsigned int rw = 0;

    #pragma unroll 1
    for (int p = 0; p < groups + 3; ++p) {
        const int k = p - w;
        if (k >= 0 && k < groups) {
            const int c = k << 5;
            const bool PREg = ((k >> 1) == w);   // e-mask only in own window
            float bv[32];
            if (w > 0) {
                const float* bp = bnd[w - 1];
                #pragma unroll
                for (int j = 0; j < 32; ++j) bv[j] = bp[(c - 1 + j) & 127];
            } else {
                #pragma unroll
                for (int j = 0; j < 32; ++j) bv[j] = NEGV;
            }
            #pragma unroll
            for (int j = 0; j < 32; ++j) {
                const int sC = c + j;
                if (j == 0 && k == 0) {
                    // col 0 init: where(t==0, lp, NEG)
                    v = tzero ? r[0] : NEGV;
                } else {
                    // values of col sC-1: v (own row), below (row-1)
                    float a = wshr1(v);
                    float below = isL0 ? bv[j] : a;
                    bool e = PREg && (row == sC);
                    bool mv = (!tzero) && (e || (below > v));
                    if (mv) rw |= (1u << j);
                    float vc = e ? NEGV : v;
                    float vp = tzero ? NEGV : below;
                    v = r[j] + fmaxf(vc, vp);
                }
                if (pub) bnd[w][sC & 127] = v;
                int cc = sC + 32; if (cc > TY_ - 1) cc = TY_ - 1;
                r[j] = base[(size_t)cc * TX_];      // prefetch next group
            }
            RB[row][k] = rw; rw = 0;               // flush word k
        }
        __syncthreads();
    }

    if (tid == 0) {
        // run-length backtrack with speculative 'below' word prefetch.
        int idx = xlen - 1;
        int yi = ylen - 1;
        int wd = yi >> 5;
        unsigned int cur = RB[idx][wd];
        unsigned int below = (idx > 0) ? RB[idx - 1][wd] : 0u;
        while (yi >= 0) {
            unsigned int m = cur & (0xFFFFFFFFu >> (31 - (yi & 31)));
            if (m) {
                int hb = 31 - __clz(m);
                int lo = (wd << 5) + hb;          // move happens at col lo
                for (int q = lo; q <= yi; ++q) PT[q] = (unsigned char)idx;
                --idx;
                cur = below;
                below = (idx > 0) ? RB[idx - 1][wd] : 0u;
                yi = lo - 1;
                if (yi >= 0 && (yi >> 5) < wd) {
                    wd = yi >> 5;
                    cur = RB[idx][wd];
                    below = (idx > 0) ? RB[idx - 1][wd] : 0u;
                }
            } else {
                int lo = wd << 5;
                for (int q = lo; q <= yi; ++q) PT[q] = (unsigned char)idx;
                yi = lo - 1;
                if (yi >= 0) {
                    --wd;
                    cur = RB[idx][wd];
                    below = (idx > 0) ? RB[idx - 1][wd] : 0u;
                }
            }
        }
    }
    __syncthreads();
    ((unsigned int*)(path + b * TY_))[tid] = PTw[tid];
}

// ---------------- K3: materialize one-hot output ------------------------
__global__ __launch_bounds__(256) void k3_out(const unsigned char* __restrict__ path,
                                              const int* __restrict__ ylens,
                                              float* __restrict__ out) {
    int F = blockIdx.x * 256 + threadIdx.x;       // float4 index, 2M total
    int yi = (F & 255) * 4;
    int t  = (F >> 8) & 255;
    int b  = F >> 16;
    int ylen = ylens[b];
    unsigned int pw = *(const unsigned int*)(path + b * TY_ + yi);
    float4 v;
    v.x = (((pw      ) & 255u) == (unsigned)t && yi     < ylen) ? 1.f : 0.f;
    v.y = (((pw >>  8) & 255u) == (unsigned)t && yi + 1 < ylen) ? 1.f : 0.f;
    v.z = (((pw >> 16) & 255u) == (unsigned)t && yi + 2 < ylen) ? 1.f : 0.f;
    v.w = (((pw >> 24) & 255u) == (unsigned)t && yi + 3 < ylen) ? 1.f : 0.f;
    ((float4*)out)[F] = v;
}

extern "C" void kernel_launch(void* const* d_in, const int* in_sizes, int n_in,
                              void* d_out, int out_size, void* d_ws, size_t ws_size,
                              hipStream_t stream) {
    const float* x  = (const float*)d_in[0];
    const int*   xl = (const int*)d_in[1];
    const float* y  = (const float*)d_in[2];
    const int*   yl = (const int*)d_in[3];
    float* out = (float*)d_out;

    char* ws = (char*)d_ws;
    float* xsq = (float*)ws;                           //  32 KB
    float* ysq = (float*)(ws + 32 * 1024);             // 128 KB
    unsigned char* path = (unsigned char*)(ws + 160 * 1024); // 32 KB

    // reuse d_out (exactly B*TY*TX floats = 32 MB) as log_prior scratch;
    // K3 fully overwrites it afterwards.
    float* lp = out;

    k0_sq  <<<160, 256, 0, stream>>>(x, y, xsq, ysq);
    k1_gemm<<<512, 256, 0, stream>>>(x, y, xsq, ysq, lp);
    k2_dp  <<<B_, 256, 0, stream>>>(lp, xl, yl, path);
    k3_out <<<(B_ * TX_ * TY_ / 4) / 256, 256, 0, stream>>>(path, yl, out);
}